// Round 3
// baseline (857.936 us; speedup 1.0000x reference)
//
#include <hip/hip_runtime.h>
#include <cmath>

#define N_B 32
#define C_B 64
#define D_B 128
#define DD  (D_B*D_B)          // 16384
#define LDP 132                // padded LDS leading dim (+4 floats)
#define BUF (D_B*LDP)          // 16896 floats per tile buffer
#define SMEM_FLOATS (2*BUF + D_B*16 + D_B + D_B + 16)
#define SMEM_BYTES  (SMEM_FLOATS*4)

#define COMP(v,t) ((t)==0?(v).x:(t)==1?(v).y:(t)==2?(v).z:(v).w)

// ---------------- K0: rdi[n,c,i] = 1/sqrt(max(|in[n,c,i,i]|,1e-4)) ----------------
__global__ void k_rdi(const float* __restrict__ in, float* __restrict__ rdi) {
    int t = blockIdx.x * 256 + threadIdx.x;       // [0, N*C*D)
    int i = t & (D_B - 1);
    int mat = t >> 7;                              // n*C + c
    float v = fabsf(in[(size_t)mat * DD + (size_t)i * D_B + i]);
    rdi[t] = 1.0f / sqrtf(fmaxf(v, 1e-4f));
}

// ---------------- K1: XWQ / XWK channel mix, X computed on the fly ----------------
__global__ __launch_bounds__(256, 2) void k_mix(
        const float* __restrict__ in, const float* __restrict__ rdi,
        const float* __restrict__ wq, const float* __restrict__ wk,
        float* __restrict__ xwq, float* __restrict__ xwk) {
    __shared__ float wqs[C_B*C_B];
    __shared__ float wks[C_B*C_B];
    const int tid = threadIdx.x;
    #pragma unroll
    for (int q = 0; q < 16; ++q) {
        wqs[q*256 + tid] = wq[q*256 + tid];
        wks[q*256 + tid] = wk[q*256 + tid];
    }
    __syncthreads();
    const int n = blockIdx.y;
    const int p = blockIdx.x * 256 + tid;          // pixel within D*D
    const int i = p >> 7, j = p & (D_B - 1);
    const float* inb  = in  + (size_t)n * C_B * DD + p;
    const float* rdib = rdi + (size_t)n * C_B * D_B;
    float accq[C_B], acck[C_B];
    #pragma unroll
    for (int k = 0; k < C_B; ++k) { accq[k] = 0.f; acck[k] = 0.f; }
    float xraw = inb[0];
    for (int c = 0; c < C_B; ++c) {
        float x = xraw * rdib[c*D_B + i] * rdib[c*D_B + j];
        x = fminf(fmaxf(x, -1.f), 1.f);
        if (c + 1 < C_B) xraw = inb[(size_t)(c+1) * DD];   // prefetch next channel
        const float4* wq4 = (const float4*)(wqs + c*C_B);
        const float4* wk4 = (const float4*)(wks + c*C_B);
        #pragma unroll
        for (int k4 = 0; k4 < 16; ++k4) {
            float4 a = wq4[k4];
            float4 b = wk4[k4];
            accq[4*k4+0] += x*a.x; accq[4*k4+1] += x*a.y;
            accq[4*k4+2] += x*a.z; accq[4*k4+3] += x*a.w;
            acck[4*k4+0] += x*b.x; acck[4*k4+1] += x*b.y;
            acck[4*k4+2] += x*b.z; acck[4*k4+3] += x*b.w;
        }
    }
    float* oq = xwq + (size_t)n * C_B * DD + p;
    float* ok = xwk + (size_t)n * C_B * DD + p;
    #pragma unroll
    for (int k = 0; k < C_B; ++k) {
        oq[(size_t)k*DD] = accq[k];
        ok[(size_t)k*DD] = acck[k];
    }
}

// ---------------- K2: per-(n,k) core: bilinear form, soft_pd_max, AXA, residual ----
__global__ __launch_bounds__(512, 2) void k_core(
        const float* __restrict__ in, const float* __restrict__ rdi,
        const float* xwq,                       // aliases `out` — intentionally not restrict
        const float* __restrict__ xwk,
        const float* __restrict__ lam, float* out) {
    extern __shared__ float sm[];
    float* bufA = sm;                  // XWQ -> T1 -> A^T
    float* bufB = sm + BUF;            // XWK -> X  -> T2
    float* rs   = sm + 2*BUF;          // [128][16] row partial sums
    float* dia  = rs + D_B*16;         // [128]
    float* rdl  = dia + D_B;           // [128]
    float* wred = rdl + D_B;           // [16]

    const int tid = threadIdx.x;
    const int bid = blockIdx.x;                 // n*64 + k
    const size_t base = (size_t)bid * DD;
    const int rg = tid >> 4, cg = tid & 15;
    const int r0 = rg * 4, j0 = cg * 8;         // 4x8 output tile per thread
    const int srow = tid >> 2, scol = (tid & 3) * 32;   // staging map: 32 floats/thread

    // ---- stage XWQ -> bufA, XWK -> bufB
    {
        const float* gq = xwq + base + (size_t)srow*D_B + scol;
        const float* gk = xwk + base + (size_t)srow*D_B + scol;
        float* da = bufA + srow*LDP + scol;
        float* db = bufB + srow*LDP + scol;
        #pragma unroll
        for (int t = 0; t < 8; ++t) {
            *(float4*)(da + 4*t) = *(const float4*)(gq + 4*t);
            *(float4*)(db + 4*t) = *(const float4*)(gk + 4*t);
        }
    }
    __syncthreads();

    // ---- T1 = XWK^T @ XWQ : T1[r][j] = sum_kk XWK[kk][r] * XWQ[kk][j]
    float acc[4][8];
    #pragma unroll
    for (int i = 0; i < 4; ++i)
        #pragma unroll
        for (int j = 0; j < 8; ++j) acc[i][j] = 0.f;
    #pragma unroll 4
    for (int kk = 0; kk < D_B; ++kk) {
        float4 a  = *(const float4*)(bufB + kk*LDP + r0);
        float4 b0 = *(const float4*)(bufA + kk*LDP + j0);
        float4 b1 = *(const float4*)(bufA + kk*LDP + j0 + 4);
        float av[4] = {a.x, a.y, a.z, a.w};
        float bv[8] = {b0.x,b0.y,b0.z,b0.w,b1.x,b1.y,b1.z,b1.w};
        #pragma unroll
        for (int i = 0; i < 4; ++i)
            #pragma unroll
            for (int j = 0; j < 8; ++j) acc[i][j] += av[i]*bv[j];
    }
    __syncthreads();
    // write T1 -> bufA (XWQ consumed)
    #pragma unroll
    for (int i = 0; i < 4; ++i) {
        float4 v0 = {acc[i][0],acc[i][1],acc[i][2],acc[i][3]};
        float4 v1 = {acc[i][4],acc[i][5],acc[i][6],acc[i][7]};
        *(float4*)(bufA + (r0+i)*LDP + j0)     = v0;
        *(float4*)(bufA + (r0+i)*LDP + j0 + 4) = v1;
    }
    // prefetch inputs tile + rdi for later X staging (hidden under next matmul)
    float4 xin[8], rcv[8];
    const float* rdib = rdi + (size_t)bid * D_B;
    const float xrr = rdib[srow];
    #pragma unroll
    for (int t = 0; t < 8; ++t) {
        xin[t] = *(const float4*)(in + base + (size_t)srow*D_B + scol + 4*t);
        rcv[t] = *(const float4*)(rdib + scol + 4*t);
    }
    __syncthreads();

    // ---- A_pre = T1 @ XWK : acc2[r][j] = sum_kk T1[r][kk]*XWK[kk][j]
    float acc2[4][8];
    #pragma unroll
    for (int i = 0; i < 4; ++i)
        #pragma unroll
        for (int j = 0; j < 8; ++j) acc2[i][j] = 0.f;
    for (int kk4 = 0; kk4 < 32; ++kk4) {
        float4 av4[4];
        #pragma unroll
        for (int i = 0; i < 4; ++i)
            av4[i] = *(const float4*)(bufA + (r0+i)*LDP + 4*kk4);
        #pragma unroll
        for (int t = 0; t < 4; ++t) {
            float4 b0 = *(const float4*)(bufB + (4*kk4+t)*LDP + j0);
            float4 b1 = *(const float4*)(bufB + (4*kk4+t)*LDP + j0 + 4);
            float bv[8] = {b0.x,b0.y,b0.z,b0.w,b1.x,b1.y,b1.z,b1.w};
            #pragma unroll
            for (int i = 0; i < 4; ++i) {
                float a = COMP(av4[i], t);
                #pragma unroll
                for (int j = 0; j < 8; ++j) acc2[i][j] += a*bv[j];
            }
        }
    }

    // ---- soft_pd_max on acc2 (whole 128x128 matrix per block)
    float m = -3.0e38f;
    #pragma unroll
    for (int i = 0; i < 4; ++i)
        #pragma unroll
        for (int j = 0; j < 8; ++j) m = fmaxf(m, acc2[i][j]);
    #pragma unroll
    for (int off = 32; off >= 1; off >>= 1) m = fmaxf(m, __shfl_xor(m, off));
    if ((tid & 63) == 0) wred[tid >> 6] = m;
    __syncthreads();
    float M = wred[0];
    #pragma unroll
    for (int w = 1; w < 8; ++w) M = fmaxf(M, wred[w]);

    float ps[4] = {0.f, 0.f, 0.f, 0.f};
    #pragma unroll
    for (int i = 0; i < 4; ++i)
        #pragma unroll
        for (int j = 0; j < 8; ++j) {
            float e = expf(acc2[i][j] - M);
            acc2[i][j] = e;
            ps[i] += e;
        }
    #pragma unroll
    for (int i = 0; i < 4; ++i) rs[(r0+i)*16 + cg] = ps[i];
    __syncthreads();
    if (tid < D_B) {
        float s = 0.f;
        #pragma unroll
        for (int c2 = 0; c2 < 16; ++c2) s += rs[tid*16 + c2];
        dia[tid] = s;
    }
    __syncthreads();
    if (tid < 64) {
        float s = dia[tid] + dia[tid + 64];
        #pragma unroll
        for (int off = 32; off >= 1; off >>= 1) s += __shfl_xor(s, off);
        if (tid == 0) wred[8] = s;
    }
    __syncthreads();
    const float total = wred[8];
    if (tid < D_B) {
        float d = dia[tid];
        d = fmaxf(d, total * 1e-5f);   // sum(dia)/100000
        d = fmaxf(d, 1e-5f);
        rdl[tid] = 1.0f / sqrtf(d);
    }
    __syncthreads();

    // A = e * rdl[r] * rdl[c]; store A^T into bufA; store X into bufB
    float rrv[4], rcw[8];
    #pragma unroll
    for (int i = 0; i < 4; ++i) rrv[i] = rdl[r0+i];
    #pragma unroll
    for (int j = 0; j < 8; ++j) rcw[j] = rdl[j0+j];
    #pragma unroll
    for (int i = 0; i < 4; ++i)
        #pragma unroll
        for (int j = 0; j < 8; ++j) acc2[i][j] *= rrv[i]*rcw[j];
    #pragma unroll
    for (int jj = 0; jj < 8; ++jj) {
        float4 v = {acc2[0][jj], acc2[1][jj], acc2[2][jj], acc2[3][jj]};
        *(float4*)(bufA + (j0+jj)*LDP + r0) = v;   // A^T[col][row]
    }
    #pragma unroll
    for (int t = 0; t < 8; ++t) {
        float4 x = xin[t], rq = rcv[t];
        x.x = fminf(fmaxf(x.x*xrr*rq.x, -1.f), 1.f);
        x.y = fminf(fmaxf(x.y*xrr*rq.y, -1.f), 1.f);
        x.z = fminf(fmaxf(x.z*xrr*rq.z, -1.f), 1.f);
        x.w = fminf(fmaxf(x.w*xrr*rq.w, -1.f), 1.f);
        *(float4*)(bufB + srow*LDP + scol + 4*t) = x;
    }
    __syncthreads();

    // ---- T2 = A @ X : T2[r][j] = sum_kk AT[kk][r] * X[kk][j]
    float acc3[4][8];
    #pragma unroll
    for (int i = 0; i < 4; ++i)
        #pragma unroll
        for (int j = 0; j < 8; ++j) acc3[i][j] = 0.f;
    #pragma unroll 4
    for (int kk = 0; kk < D_B; ++kk) {
        float4 a  = *(const float4*)(bufA + kk*LDP + r0);
        float4 b0 = *(const float4*)(bufB + kk*LDP + j0);
        float4 b1 = *(const float4*)(bufB + kk*LDP + j0 + 4);
        float av[4] = {a.x, a.y, a.z, a.w};
        float bv[8] = {b0.x,b0.y,b0.z,b0.w,b1.x,b1.y,b1.z,b1.w};
        #pragma unroll
        for (int i = 0; i < 4; ++i)
            #pragma unroll
            for (int j = 0; j < 8; ++j) acc3[i][j] += av[i]*bv[j];
    }
    __syncthreads();
    // write T2 -> bufB (X consumed)
    #pragma unroll
    for (int i = 0; i < 4; ++i) {
        float4 v0 = {acc3[i][0],acc3[i][1],acc3[i][2],acc3[i][3]};
        float4 v1 = {acc3[i][4],acc3[i][5],acc3[i][6],acc3[i][7]};
        *(float4*)(bufB + (r0+i)*LDP + j0)     = v0;
        *(float4*)(bufB + (r0+i)*LDP + j0 + 4) = v1;
    }
    __syncthreads();

    // ---- AXA = T2 @ A^T : acc4[r][j] = sum_kk T2[r][kk] * AT[kk][j]
    float acc4[4][8];
    #pragma unroll
    for (int i = 0; i < 4; ++i)
        #pragma unroll
        for (int j = 0; j < 8; ++j) acc4[i][j] = 0.f;
    for (int kk4 = 0; kk4 < 32; ++kk4) {
        float4 av4[4];
        #pragma unroll
        for (int i = 0; i < 4; ++i)
            av4[i] = *(const float4*)(bufB + (r0+i)*LDP + 4*kk4);
        #pragma unroll
        for (int t = 0; t < 4; ++t) {
            float4 b0 = *(const float4*)(bufA + (4*kk4+t)*LDP + j0);
            float4 b1 = *(const float4*)(bufA + (4*kk4+t)*LDP + j0 + 4);
            float bv[8] = {b0.x,b0.y,b0.z,b0.w,b1.x,b1.y,b1.z,b1.w};
            #pragma unroll
            for (int i = 0; i < 4; ++i) {
                float a = COMP(av4[i], t);
                #pragma unroll
                for (int j = 0; j < 8; ++j) acc4[i][j] += a*bv[j];
            }
        }
    }

    // ---- epilogue: out = inputs + lam * AXA
    const float l = lam[bid & 63];
    #pragma unroll
    for (int i = 0; i < 4; ++i) {
        #pragma unroll
        for (int q = 0; q < 2; ++q) {
            float4 vin = *(const float4*)(in + base + (size_t)(r0+i)*D_B + j0 + 4*q);
            float4 o;
            o.x = vin.x + l*acc4[i][4*q+0];
            o.y = vin.y + l*acc4[i][4*q+1];
            o.z = vin.z + l*acc4[i][4*q+2];
            o.w = vin.w + l*acc4[i][4*q+3];
            *(float4*)(out + base + (size_t)(r0+i)*D_B + j0 + 4*q) = o;
        }
    }
}

extern "C" void kernel_launch(void* const* d_in, const int* in_sizes, int n_in,
                              void* d_out, int out_size, void* d_ws, size_t ws_size,
                              hipStream_t stream) {
    const float* in  = (const float*)d_in[0];
    const float* wq  = (const float*)d_in[1];
    const float* wk  = (const float*)d_in[2];
    const float* lam = (const float*)d_in[3];
    float* out = (float*)d_out;

    // workspace layout: XWK (N*C*D*D floats) then rdi (N*C*D floats)
    float* xwk = (float*)d_ws;
    float* rdi = xwk + (size_t)N_B*C_B*DD;
    // XWQ lives in d_out: block (n,k) is the only consumer of XWQ[n,k] and
    // reads it into LDS before writing its output slice there.
    float* xwq = out;

    hipFuncSetAttribute((const void*)k_core,
                        hipFuncAttributeMaxDynamicSharedMemorySize, SMEM_BYTES);

    k_rdi<<<(N_B*C_B*D_B)/256, 256, 0, stream>>>(in, rdi);
    k_mix<<<dim3(DD/256, N_B), 256, 0, stream>>>(in, rdi, wq, wk, xwq, xwk);
    k_core<<<N_B*C_B, 512, SMEM_BYTES, stream>>>(in, rdi, xwq, xwk, lam, out);
}